// Round 4
// baseline (386.660 us; speedup 1.0000x reference)
//
#include <hip/hip_runtime.h>

// FGPillarMaxPooling on MI355X (gfx950) — v5: index-binned gather-pool.
//
// Empirical laws from R0-R3 counters:
//  - Output writes cap at ~0.9-1.3 TB/s however issued (memset 0.96, streaming
//    zero 0.93, scattered atomic writeback ~0.9, fill_empty gaps 0.47,
//    R1 gather-pool 1.31 = best). Atomic op count is irrelevant (R2:
//    predication changed nothing). Touched-map side stores cost +32 µs (R3).
//  - Inputs are tiny (22.4 MB) -> L3-resident; reads are cheap.
// => Optimal: write the 134 MB output EXACTLY ONCE, contiguously (pool pass,
//    measured 102 µs in R1), and make binning prep near-free. R1's prep was
//    210 µs because it scattered 32B records; v5 scatters 4B indices instead
//    and keeps all binning state (~14.6 MB) L2-scale.
//
// Passes:
//  1) pass_count:   seg per point -> seg_arr (3.2 MB), histogram atomicAdd
//                   into counts (4 MB, L2-resident).
//  2) pass_scan:    exclusive scan of counts -> cursor (block scan + one
//                   global atomicAdd per 1024-cell chunk). Verified in R1.
//  3) pass_scatter: slot = atomicAdd(cursor[seg]); idx[slot] = p. 4B writes
//                   into 3.2 MB (L2-resident).  After: cursor[cell] == end.
//  4) pass_pool:    lane=(cell,channel); loop idx[start..end), gather
//                   xyz/feat (L3-hit broadcasts), 7 FMA, relu, max; one
//                   coalesced 128B nontemporal store per cell. Empty -> 0.
//                   No output pre-zero needed anywhere.

#define GW 512
#define GH 512
#define COUT 32

__device__ __forceinline__ int batch_of(int p, const int* __restrict__ cnt, int B) {
    int b = 0, acc = 0;
    for (int k = 0; k < B; ++k) { acc += cnt[k]; b += (p >= acc) ? 1 : 0; }
    return min(b, B - 1);
}

__device__ __forceinline__ void cell_of(float x, float y, int& px, int& py) {
    // keep IEEE division to match the reference's floor decisions
    px = (int)floorf((x - (-51.2f)) / 0.2f);
    py = (int)floorf((y - (-51.2f)) / 0.2f);
    px = min(max(px, 0), GW - 1);
    py = min(max(py, 0), GH - 1);
}

__global__ __launch_bounds__(256) void pass_count(
    const float* __restrict__ xyz, const int* __restrict__ cnt,
    unsigned* __restrict__ counts, unsigned* __restrict__ seg_arr,
    int N, int B)
{
    int p = blockIdx.x * 256 + threadIdx.x;
    if (p >= N) return;
    float x = xyz[3 * p + 0];
    float y = xyz[3 * p + 1];
    int px, py; cell_of(x, y, px, py);
    int b = batch_of(p, cnt, B);
    unsigned seg = (unsigned)b * (GH * GW) + (unsigned)py * GW + (unsigned)px;
    seg_arr[p] = seg;
    atomicAdd(&counts[seg], 1u);
}

__global__ __launch_bounds__(256) void pass_scan(
    const unsigned* __restrict__ counts, unsigned* __restrict__ cursor,
    unsigned* __restrict__ gcur, int ncells)
{
    __shared__ unsigned waveOff[4];
    __shared__ unsigned blockBase;
    int tid = threadIdx.x;
    int base = (blockIdx.x * 256 + tid) * 4;

    uint4 cv = make_uint4(0u, 0u, 0u, 0u);
    if (base + 3 < ncells) {
        cv = *(const uint4*)(counts + base);
    } else if (base < ncells) {
        cv.x = counts[base];
        if (base + 1 < ncells) cv.y = counts[base + 1];
        if (base + 2 < ncells) cv.z = counts[base + 2];
    }
    unsigned lsum = cv.x + cv.y + cv.z + cv.w;

    // inclusive scan across the 64-lane wave
    unsigned s = lsum;
    int lane = tid & 63;
    #pragma unroll
    for (int d = 1; d < 64; d <<= 1) {
        unsigned t = __shfl_up(s, d, 64);
        if (lane >= d) s += t;
    }
    int wv = tid >> 6;
    if (lane == 63) waveOff[wv] = s;
    __syncthreads();
    if (tid == 0) {
        unsigned w0 = waveOff[0], w1 = waveOff[1], w2 = waveOff[2], w3 = waveOff[3];
        blockBase = atomicAdd(gcur, w0 + w1 + w2 + w3);
        waveOff[0] = 0; waveOff[1] = w0; waveOff[2] = w0 + w1; waveOff[3] = w0 + w1 + w2;
    }
    __syncthreads();

    unsigned start = blockBase + waveOff[wv] + (s - lsum);  // exclusive base
    uint4 o;
    o.x = start;
    o.y = o.x + cv.x;
    o.z = o.y + cv.y;
    o.w = o.z + cv.z;
    if (base + 3 < ncells) {
        *(uint4*)(cursor + base) = o;
    } else if (base < ncells) {
        cursor[base] = o.x;
        if (base + 1 < ncells) cursor[base + 1] = o.y;
        if (base + 2 < ncells) cursor[base + 2] = o.z;
    }
}

__global__ __launch_bounds__(256) void pass_scatter(
    const unsigned* __restrict__ seg_arr, unsigned* __restrict__ cursor,
    unsigned* __restrict__ idx, int N)
{
    int p = blockIdx.x * 256 + threadIdx.x;
    if (p >= N) return;
    unsigned slot = atomicAdd(&cursor[seg_arr[p]], 1u);  // after: cursor==end
    idx[slot] = (unsigned)p;
}

__global__ __launch_bounds__(256) void pass_pool(
    const unsigned* __restrict__ counts, const unsigned* __restrict__ cursor,
    const unsigned* __restrict__ idx,
    const float* __restrict__ xyz, const float4* __restrict__ feat,
    const float* __restrict__ W,
    float* __restrict__ out, int ncells)
{
    int tid = threadIdx.x;
    int cell = blockIdx.x * 8 + (tid >> 5);
    int c = tid & 31;
    if (cell >= ncells) return;

    // per-lane weight column (896B total, L1-resident after first block)
    float w0 = W[0 * COUT + c], w1 = W[1 * COUT + c], w2 = W[2 * COUT + c];
    float w3 = W[3 * COUT + c], w4 = W[4 * COUT + c], w5 = W[5 * COUT + c];
    float w6 = W[6 * COUT + c];

    unsigned end = cursor[cell];
    unsigned num = counts[cell];

    float best = 0.0f;  // relu >= 0; empty cells stay exactly 0
    for (unsigned i = end - num; i < end; ++i) {
        unsigned p = idx[i];                    // broadcast within group
        float x = xyz[3 * p + 0];               // L3-resident gathers
        float y = xyz[3 * p + 1];
        float z = xyz[3 * p + 2];
        float4 f = feat[p];
        int px, py; cell_of(x, y, px, py);
        float cx = ((float)px + 0.5f) * 0.2f + (-51.2f);
        float cy = ((float)py + 0.5f) * 0.2f + (-51.2f);
        float h = f.x * w0 + f.y * w1 + f.z * w2 + f.w * w3
                + (x - cx) * w4 + (y - cy) * w5 + (z + 1.0f) * w6;
        best = fmaxf(best, h);
    }
    // one coalesced 128B line per cell; bypass L2 on the way out
    __builtin_nontemporal_store(best, out + (size_t)cell * COUT + c);
}

// ---------------- fallback (if workspace too small): pre-zero + unsigned max

#define PTS_PER_BLOCK 8

__global__ __launch_bounds__(256) void zero_out(uint4* __restrict__ out, int n4)
{
    int stride = gridDim.x * 256;
    for (int i = blockIdx.x * 256 + threadIdx.x; i < n4; i += stride)
        out[i] = make_uint4(0u, 0u, 0u, 0u);
}

__global__ __launch_bounds__(256) void pillar_fwd_zeroed(
    const float* __restrict__ xyz, const int* __restrict__ cnt,
    const float4* __restrict__ feat, const float* __restrict__ W,
    unsigned int* __restrict__ out, int N, int B)
{
    __shared__ float sW[7 * COUT];
    int tid = threadIdx.x;
    if (tid < 7 * COUT) sW[tid] = W[tid];
    __syncthreads();
    int p = blockIdx.x * PTS_PER_BLOCK + (tid >> 5);
    int c = tid & 31;
    if (p >= N) return;
    float x = xyz[3 * p + 0], y = xyz[3 * p + 1], z = xyz[3 * p + 2];
    int b = batch_of(p, cnt, B);
    int px, py; cell_of(x, y, px, py);
    float cx = ((float)px + 0.5f) * 0.2f + (-51.2f);
    float cy = ((float)py + 0.5f) * 0.2f + (-51.2f);
    float4 f = feat[p];
    float h = f.x * sW[0 * COUT + c] + f.y * sW[1 * COUT + c]
            + f.z * sW[2 * COUT + c] + f.w * sW[3 * COUT + c]
            + (x - cx) * sW[4 * COUT + c] + (y - cy) * sW[5 * COUT + c]
            + (z + 1.0f) * sW[6 * COUT + c];
    h = fmaxf(h, 0.0f);
    unsigned seg = (unsigned)b * (GH * GW) + (unsigned)py * GW + (unsigned)px;
    atomicMax(out + (size_t)seg * COUT + c, __float_as_uint(h));
}

extern "C" void kernel_launch(void* const* d_in, const int* in_sizes, int n_in,
                              void* d_out, int out_size, void* d_ws, size_t ws_size,
                              hipStream_t stream) {
    const float*  xyz  = (const float*)d_in[0];
    const int*    cnt  = (const int*)d_in[1];
    const float4* feat = (const float4*)d_in[2];
    const float*  W    = (const float*)d_in[3];

    int N = in_sizes[0] / 3;
    int B = in_sizes[1];
    int ncells = B * GH * GW;

    // ws layout: [gcur pad 256B][counts 4MB][cursor 4MB][seg_arr 3.2MB][idx 3.2MB]
    size_t offCounts = 256;
    size_t offCursor = offCounts + (size_t)ncells * 4;
    size_t offSeg    = offCursor + (size_t)ncells * 4;
    size_t offIdx    = offSeg + (size_t)N * 4;
    size_t needed    = offIdx + (size_t)N * 4;

    if (ws_size >= needed) {
        char* ws = (char*)d_ws;
        unsigned* counts  = (unsigned*)(ws + offCounts);
        unsigned* cursor  = (unsigned*)(ws + offCursor);
        unsigned* seg_arr = (unsigned*)(ws + offSeg);
        unsigned* idx     = (unsigned*)(ws + offIdx);
        unsigned* gcur    = (unsigned*)ws;

        // zero gcur + counts only (~4.2 MB)
        hipMemsetAsync(ws, 0, offCursor, stream);

        int gpts = (N + 255) / 256;
        pass_count  <<<gpts, 256, 0, stream>>>(xyz, cnt, counts, seg_arr, N, B);
        pass_scan   <<<(ncells + 1023) / 1024, 256, 0, stream>>>(counts, cursor, gcur, ncells);
        pass_scatter<<<gpts, 256, 0, stream>>>(seg_arr, cursor, idx, N);
        pass_pool   <<<(ncells + 7) / 8, 256, 0, stream>>>(counts, cursor, idx,
                                                           xyz, feat, W,
                                                           (float*)d_out, ncells);
    } else {
        int n4 = out_size / 4;
        zero_out<<<2048, 256, 0, stream>>>((uint4*)d_out, n4);
        int grid = (N + PTS_PER_BLOCK - 1) / PTS_PER_BLOCK;
        pillar_fwd_zeroed<<<grid, 256, 0, stream>>>(xyz, cnt, feat, W,
                                                    (unsigned int*)d_out, N, B);
    }
}

// Round 5
// 319.143 us; speedup vs baseline: 1.2116x; 1.2116x over previous
//
#include <hip/hip_runtime.h>

// FGPillarMaxPooling on MI355X (gfx950) — v6: in-line bucketing.
//
// Measured laws (R0-R4):
//  - Dense full-line coalesced writes of the 134MB output: 1.31 TB/s (best).
//  - Scattered atomics/stores into d_out: fine (25.6M ops in 113 µs).
//  - Index-gather pool: FETCH blows up 3.6x, +67 µs (R4). Records must be
//    read contiguously.
//  - Prep passes that scatter into d_ws: ~213 µs regardless of payload size
//    (R1 32B vs R4 4B) -> suspect ws ops are slow; this round keeps ONLY the
//    800k counter atomics in ws (diagnostic), all bulk data lives in d_out.
//
// v6: each 128B output line doubles as the record bucket for its own cell.
//  phase1 bucket_scatter: slot=atomicAdd(cnt[seg]); slot<4 -> store 7-float
//          record {f0..f3,g4,g5,g6} at out[seg*32+slot*7] (words 0..27).
//          slot>=4 -> ws overflow list (cap >= N: exact for any input;
//          expected ~1.3k points at Poisson(0.76)).
//  phase2 pool_lines: 32 lanes per cell; read own line's records (contiguous,
//          L3-hot), h = rec @ W, relu, max; rewrite the full line once.
//          Empty cells -> exact 0. No output pre-zero pass at all.
//  phase3 overflow_fix: signed atomicMax of overflow points into the (now
//          valid, non-negative) lines. Monotone + order-independent -> exact.

#define GW 512
#define GH 512
#define COUT 32
#define CAP 4     // records per output line
#define RECF 7    // floats per record

struct OvRec { unsigned seg; float f0, f1, f2, f3, g4, g5, g6; };  // 32B

__device__ __forceinline__ int batch_of(int p, const int* __restrict__ cnt, int B) {
    int b = 0, acc = 0;
    for (int k = 0; k < B; ++k) { acc += cnt[k]; b += (p >= acc) ? 1 : 0; }
    return min(b, B - 1);
}

__device__ __forceinline__ void cell_of(float x, float y, int& px, int& py) {
    // keep IEEE division to match the reference's floor decisions
    px = (int)floorf((x - (-51.2f)) / 0.2f);
    py = (int)floorf((y - (-51.2f)) / 0.2f);
    px = min(max(px, 0), GW - 1);
    py = min(max(py, 0), GH - 1);
}

__global__ __launch_bounds__(256) void bucket_scatter(
    const float* __restrict__ xyz, const int* __restrict__ cnt,
    const float4* __restrict__ feat,
    unsigned* __restrict__ counts,      // ws: (ncells) zeroed
    unsigned* __restrict__ gcount,      // ws: overflow counter, zeroed
    OvRec* __restrict__ list,           // ws: overflow records
    unsigned ocap,
    float* __restrict__ out,            // poisoned; words 0..27 become records
    int N, int B)
{
    int p = blockIdx.x * 256 + threadIdx.x;
    if (p >= N) return;
    float x = xyz[3 * p + 0];
    float y = xyz[3 * p + 1];
    float z = xyz[3 * p + 2];
    int b = batch_of(p, cnt, B);
    int px, py; cell_of(x, y, px, py);
    float cx = ((float)px + 0.5f) * 0.2f + (-51.2f);
    float cy = ((float)py + 0.5f) * 0.2f + (-51.2f);
    float g4 = x - cx, g5 = y - cy, g6 = z + 1.0f;
    float4 f = feat[p];
    unsigned seg = (unsigned)b * (GH * GW) + (unsigned)py * GW + (unsigned)px;

    unsigned slot = atomicAdd(&counts[seg], 1u);
    if (slot < CAP) {
        float* dst = out + (size_t)seg * COUT + slot * RECF;
        dst[0] = f.x; dst[1] = f.y; dst[2] = f.z; dst[3] = f.w;
        dst[4] = g4;  dst[5] = g5;  dst[6] = g6;
    } else {
        unsigned oi = atomicAdd(gcount, 1u);
        if (oi < ocap) {
            OvRec r; r.seg = seg;
            r.f0 = f.x; r.f1 = f.y; r.f2 = f.z; r.f3 = f.w;
            r.g4 = g4;  r.g5 = g5;  r.g6 = g6;
            list[oi] = r;
        }
    }
}

__global__ __launch_bounds__(256) void pool_lines(
    const unsigned* __restrict__ counts, const float* __restrict__ W,
    float* __restrict__ out, int ncells)
{
    int tid = threadIdx.x;
    int cell = blockIdx.x * 8 + (tid >> 5);
    int c = tid & 31;
    if (cell >= ncells) return;

    float w0 = W[0 * COUT + c], w1 = W[1 * COUT + c], w2 = W[2 * COUT + c];
    float w3 = W[3 * COUT + c], w4 = W[4 * COUT + c], w5 = W[5 * COUT + c];
    float w6 = W[6 * COUT + c];

    unsigned m = counts[cell];
    if (m > CAP) m = CAP;
    const float* line = out + (size_t)cell * COUT;

    float best = 0.0f;   // relu >= 0; empty cells -> exact 0
    for (unsigned j = 0; j < m; ++j) {
        // uniform-address loads within the 32-lane group; the line is L3-hot
        // from phase1. All loads complete (data needed for 'best') before the
        // store below issues -> in-place rewrite is safe.
        float f0 = line[j * RECF + 0], f1 = line[j * RECF + 1];
        float f2 = line[j * RECF + 2], f3 = line[j * RECF + 3];
        float g4 = line[j * RECF + 4], g5 = line[j * RECF + 5];
        float g6 = line[j * RECF + 6];
        float h = f0 * w0 + f1 * w1 + f2 * w2 + f3 * w3
                + g4 * w4 + g5 * w5 + g6 * w6;
        best = fmaxf(best, h);
    }
    out[(size_t)cell * COUT + c] = best;  // full 128B line per group, once
}

__global__ __launch_bounds__(256) void overflow_fix(
    const unsigned* __restrict__ gcount, const OvRec* __restrict__ list,
    const float* __restrict__ W, int* __restrict__ out, unsigned ocap)
{
    __shared__ float sW[RECF * COUT];
    int tid = threadIdx.x;
    if (tid < RECF * COUT) sW[tid] = W[tid];
    __syncthreads();

    unsigned total = *gcount;
    if (total > ocap) total = ocap;
    int c = tid & 31;
    unsigned stride = gridDim.x * 8;
    for (unsigned i = blockIdx.x * 8 + (tid >> 5); i < total; i += stride) {
        OvRec r = list[i];
        float h = r.f0 * sW[0 * COUT + c] + r.f1 * sW[1 * COUT + c]
                + r.f2 * sW[2 * COUT + c] + r.f3 * sW[3 * COUT + c]
                + r.g4 * sW[4 * COUT + c] + r.g5 * sW[5 * COUT + c]
                + r.g6 * sW[6 * COUT + c];
        // lines are valid & non-negative after pool_lines; signed int max is
        // monotone there and negative h (sign bit set -> int < 0) never wins.
        atomicMax(out + (size_t)r.seg * COUT + c, __float_as_int(h));
    }
}

// ---------------- fallback (ws too small): pre-zero + unsigned atomicMax ----

#define PTS_PER_BLOCK 8

__global__ __launch_bounds__(256) void zero_out(uint4* __restrict__ out, int n4)
{
    int stride = gridDim.x * 256;
    for (int i = blockIdx.x * 256 + threadIdx.x; i < n4; i += stride)
        out[i] = make_uint4(0u, 0u, 0u, 0u);
}

__global__ __launch_bounds__(256) void pillar_fwd_zeroed(
    const float* __restrict__ xyz, const int* __restrict__ cnt,
    const float4* __restrict__ feat, const float* __restrict__ W,
    unsigned int* __restrict__ out, int N, int B)
{
    __shared__ float sW[RECF * COUT];
    int tid = threadIdx.x;
    if (tid < RECF * COUT) sW[tid] = W[tid];
    __syncthreads();
    int p = blockIdx.x * PTS_PER_BLOCK + (tid >> 5);
    int c = tid & 31;
    if (p >= N) return;
    float x = xyz[3 * p + 0], y = xyz[3 * p + 1], z = xyz[3 * p + 2];
    int b = batch_of(p, cnt, B);
    int px, py; cell_of(x, y, px, py);
    float cx = ((float)px + 0.5f) * 0.2f + (-51.2f);
    float cy = ((float)py + 0.5f) * 0.2f + (-51.2f);
    float4 f = feat[p];
    float h = f.x * sW[0 * COUT + c] + f.y * sW[1 * COUT + c]
            + f.z * sW[2 * COUT + c] + f.w * sW[3 * COUT + c]
            + (x - cx) * sW[4 * COUT + c] + (y - cy) * sW[5 * COUT + c]
            + (z + 1.0f) * sW[6 * COUT + c];
    h = fmaxf(h, 0.0f);
    unsigned seg = (unsigned)b * (GH * GW) + (unsigned)py * GW + (unsigned)px;
    atomicMax(out + (size_t)seg * COUT + c, __float_as_uint(h));
}

extern "C" void kernel_launch(void* const* d_in, const int* in_sizes, int n_in,
                              void* d_out, int out_size, void* d_ws, size_t ws_size,
                              hipStream_t stream) {
    const float*  xyz  = (const float*)d_in[0];
    const int*    cnt  = (const int*)d_in[1];
    const float4* feat = (const float4*)d_in[2];
    const float*  W    = (const float*)d_in[3];

    int N = in_sizes[0] / 3;
    int B = in_sizes[1];
    int ncells = B * GH * GW;

    // ws layout: [gcount pad 256B][counts ncells*4][overflow list]
    size_t offCounts = 256;
    size_t offList   = (offCounts + (size_t)ncells * 4 + 255) & ~(size_t)255;
    size_t needed    = offList + (size_t)N * sizeof(OvRec);  // ocap>=N: exact

    if (ws_size >= needed) {
        char* ws = (char*)d_ws;
        unsigned* gcount = (unsigned*)ws;
        unsigned* counts = (unsigned*)(ws + offCounts);
        OvRec*    list   = (OvRec*)(ws + offList);
        unsigned  ocap   = (unsigned)N;

        hipMemsetAsync(ws, 0, offCounts + (size_t)ncells * 4, stream);

        int gpts = (N + 255) / 256;
        bucket_scatter<<<gpts, 256, 0, stream>>>(xyz, cnt, feat, counts, gcount,
                                                 list, ocap, (float*)d_out, N, B);
        pool_lines<<<(ncells + 7) / 8, 256, 0, stream>>>(counts, W,
                                                         (float*)d_out, ncells);
        overflow_fix<<<256, 256, 0, stream>>>(gcount, list, W,
                                              (int*)d_out, ocap);
    } else {
        int n4 = out_size / 4;
        zero_out<<<2048, 256, 0, stream>>>((uint4*)d_out, n4);
        int grid = (N + PTS_PER_BLOCK - 1) / PTS_PER_BLOCK;
        pillar_fwd_zeroed<<<grid, 256, 0, stream>>>(xyz, cnt, feat, W,
                                                    (unsigned int*)d_out, N, B);
    }
}